// Round 8
// baseline (694.869 us; speedup 1.0000x reference)
//
#include <hip/hip_runtime.h>
#include <hip/hip_fp16.h>

// ---- shape constants (N=100000 <= 131072 so src fits in 17 bits) ----
#define SB_SHIFT 8
#define SB_SIZE 256             // nodes per super-bucket (sortB parallelism: nsb=391)
#define MAXSB 512               // padded super-bucket array size
#define BIN_CHUNK 8192          // edges per chunk -> 391 blocks
#define BIN_THREADS 1024        // 16 waves/block -> ~12 waves/CU
#define SRC_BITS 17
#define SRC_MASK 0x1FFFF
#define NODES_PER_BLOCK 64      // mm1 tile
#define AGG_NODES 32            // nodes per agg block (256 threads, 8/node)
#define DEGB 256                // degree buckets for counting sort

__global__ void zero_i_kernel(int* __restrict__ p, int total) {
  int i = blockIdx.x * blockDim.x + threadIdx.x;
  if (i < total) p[i] = 0;
}

// per-chunk histogram of col>>8 -> cntM[chunk][*], plus global totals bcnt
__global__ __launch_bounds__(BIN_THREADS) void histA_kernel(const int* __restrict__ col,
                                                            int* __restrict__ bcnt,
                                                            int* __restrict__ cntM,
                                                            int e, int nsb) {
  __shared__ int lc[MAXSB];
  int t = threadIdx.x;
  int chunk = blockIdx.x;
  int i0 = chunk * BIN_CHUNK;
  int i1 = min(i0 + BIN_CHUNK, e);
  if (t < MAXSB) lc[t] = 0;
  __syncthreads();
  for (int i = i0 + t; i < i1; i += BIN_THREADS)
    atomicAdd(&lc[col[i] >> SB_SHIFT], 1);
  __syncthreads();
  int* cm = cntM + (size_t)chunk * MAXSB;
  if (t < MAXSB) {
    int v = lc[t];
    cm[t] = v;
    if (t < nsb && v) atomicAdd(&bcnt[t], v);
  }
}

// exclusive scan over nsb (<=512) counts -> sbstart[0..nsb], bcur copy
__global__ __launch_bounds__(512) void scanA_kernel(const int* __restrict__ bcnt,
                                                    int* __restrict__ sbstart,
                                                    int* __restrict__ bcur, int nsb) {
  __shared__ int lds[512];
  int t = threadIdx.x;
  int v = (t < nsb) ? bcnt[t] : 0;
  lds[t] = v;
  __syncthreads();
  for (int off = 1; off < 512; off <<= 1) {
    int u = (t >= off) ? lds[t - off] : 0;
    __syncthreads();
    lds[t] += u;
    __syncthreads();
  }
  int excl = lds[t] - v;
  if (t < nsb) { sbstart[t] = excl; bcur[t] = excl; }
  if (t == 511) sbstart[nsb] = lds[511];
}

// pass A: LDS-staged radix partition into super-bucket groups.
// Scatter goes to LDS (cheap); global write is a linear sweep -> wave-coalesced
// full-line writes, bounded amplification regardless of run length.
// pairsA = src | colLow8<<17
__global__ __launch_bounds__(BIN_THREADS) void binA_kernel(const int* __restrict__ row,
                                                           const int* __restrict__ col,
                                                           const int* __restrict__ cntM,
                                                           int* __restrict__ bcur,
                                                           int* __restrict__ pairsA, int e) {
  __shared__ int stage[BIN_CHUNK];   // 32 KB staging
  __shared__ int cm[MAXSB];
  __shared__ int gbase[MAXSB];
  __shared__ int lb[MAXSB];          // exclusive local base (after scan)
  __shared__ int lcur[MAXSB];
  int t = threadIdx.x;
  int chunk = blockIdx.x;
  int i0 = chunk * BIN_CHUNK;
  int i1 = min(i0 + BIN_CHUNK, e);
  int csize = i1 - i0;
  const int* cmg = cntM + (size_t)chunk * MAXSB;
  if (t < MAXSB) {
    int c = cmg[t];
    cm[t] = c;
    gbase[t] = c ? atomicAdd(&bcur[t], c) : 0;
    lb[t] = c;
  }
  __syncthreads();
  // Hillis-Steele inclusive scan on lb[0..511]
  for (int off = 1; off < MAXSB; off <<= 1) {
    int u = (t < MAXSB && t >= off) ? lb[t - off] : 0;
    __syncthreads();
    if (t < MAXSB) lb[t] += u;
    __syncthreads();
  }
  if (t < MAXSB) {
    int ex = lb[t] - cm[t];   // exclusive base
    lb[t] = ex;
    lcur[t] = ex;
  }
  __syncthreads();
  // scatter into LDS staging, grouped by bucket
  for (int i = i0 + t; i < i1; i += BIN_THREADS) {
    int c = col[i];
    int b = c >> SB_SHIFT;
    int p = atomicAdd(&lcur[b], 1);
    stage[p] = row[i] | ((c & (SB_SIZE - 1)) << SRC_BITS);
  }
  __syncthreads();
  // linear flush: consecutive p -> consecutive dest within each bucket run
  for (int p = t; p < csize; p += BIN_THREADS) {
    int b = 0;
    #pragma unroll
    for (int step = 256; step > 0; step >>= 1) {
      int nb = b + step;
      if (nb < MAXSB && lb[nb] <= p) b = nb;
    }
    pairsA[gbase[b] + (p - lb[b])] = stage[p];
  }
}

// pass B: per super-bucket counting sort by local col -> node-sorted src array.
// node_start[], dinv[], and the degree histogram fall out of the count for free.
__global__ __launch_bounds__(512) void sortB_kernel(const int* __restrict__ pairsA,
                                                    const int* __restrict__ sbstart,
                                                    int* __restrict__ pairs,
                                                    int* __restrict__ node_start,
                                                    float* __restrict__ dinv,
                                                    int* __restrict__ degcnt, int n) {
  __shared__ int cnt[SB_SIZE];
  __shared__ int base[SB_SIZE];
  __shared__ int cur[SB_SIZE];
  int b = blockIdx.x, t = threadIdx.x;
  int e0 = sbstart[b], e1 = sbstart[b + 1];
  if (t < SB_SIZE) cnt[t] = 0;
  __syncthreads();
  for (int i = e0 + t; i < e1; i += 512) atomicAdd(&cnt[pairsA[i] >> SRC_BITS], 1);
  __syncthreads();
  if (t < SB_SIZE) base[t] = cnt[t];
  __syncthreads();
  for (int off = 1; off < SB_SIZE; off <<= 1) {
    int u = (t < SB_SIZE && t >= off) ? base[t - off] : 0;
    __syncthreads();
    if (t < SB_SIZE) base[t] += u;
    __syncthreads();
  }
  if (t < SB_SIZE) {
    int excl = base[t] - cnt[t];
    cur[t] = excl;
    int node = (b << SB_SHIFT) + t;
    node_start[node] = e0 + excl;
    dinv[node] = rsqrtf((float)cnt[t] + 1.0f);
    if (node < n) atomicAdd(&degcnt[min(cnt[t], DEGB - 1)], 1);  // free deg histogram
  }
  __syncthreads();
  for (int i = e0 + t; i < e1; i += 512) {
    int v = pairsA[i];
    int pos = e0 + atomicAdd(&cur[v >> SRC_BITS], 1);
    pairs[pos] = v & SRC_MASK;
  }
}

// exclusive scan of degree-bucket counts (256, one block)
__global__ __launch_bounds__(DEGB) void degscan_kernel(const int* __restrict__ degcnt,
                                                       int* __restrict__ degoff) {
  __shared__ int lds[DEGB];
  int t = threadIdx.x;
  int v = degcnt[t];
  lds[t] = v;
  __syncthreads();
  for (int off = 1; off < DEGB; off <<= 1) {
    int u = (t >= off) ? lds[t - off] : 0;
    __syncthreads();
    lds[t] += u;
    __syncthreads();
  }
  degoff[t] = lds[t] - v;
}

// counting-sort scatter: perm = node ids in ascending-degree order
// (order within a degree bucket arbitrary -> per-node sums unaffected)
__global__ __launch_bounds__(256) void degscat_kernel(const int* __restrict__ node_start,
                                                      int* __restrict__ degoff,
                                                      int* __restrict__ perm, int n) {
  int i = blockIdx.x * 256 + threadIdx.x;
  if (i < n) {
    int d = min(node_start[i + 1] - node_start[i], DEGB - 1);
    perm[atomicAdd(&degoff[d], 1)] = i;
  }
}

// s1 = fp16( (x @ W1) * dinv ) ; 32 B/row -> L2-resident table
__global__ __launch_bounds__(256) void mm1_kernel(const float* __restrict__ x,
                                                  const float* __restrict__ W1,
                                                  const float* __restrict__ dinv,
                                                  __half* __restrict__ s1, int n) {
  __shared__ float xs[NODES_PER_BLOCK][129];
  __shared__ float ws[128 * 16];
  int t = threadIdx.x;
  for (int i = t; i < 128 * 16; i += 256) ws[i] = W1[i];
  int base = blockIdx.x * NODES_PER_BLOCK;
  for (int i = t * 4; i < NODES_PER_BLOCK * 128; i += 256 * 4) {
    int nn = i >> 7, k = i & 127;
    if (base + nn < n) {
      float4 v = *(const float4*)(x + (size_t)(base + nn) * 128 + k);
      xs[nn][k] = v.x; xs[nn][k + 1] = v.y; xs[nn][k + 2] = v.z; xs[nn][k + 3] = v.w;
    }
  }
  __syncthreads();
  int nn = t >> 2;
  int j0 = (t & 3) * 4;
  float a0 = 0, a1 = 0, a2 = 0, a3 = 0;
  #pragma unroll 8
  for (int k = 0; k < 128; k++) {
    float xv = xs[nn][k];
    const float* wr = ws + k * 16 + j0;
    a0 += xv * wr[0]; a1 += xv * wr[1]; a2 += xv * wr[2]; a3 += xv * wr[3];
  }
  int node = base + nn;
  if (node < n) {
    float d = dinv[node];
    __half2 p0 = __floats2half2_rn(a0 * d, a1 * d);
    __half2 p1 = __floats2half2_rn(a2 * d, a3 * d);
    union { struct { __half2 a, b; } h; uint2 u; } pk;
    pk.h.a = p0; pk.h.b = p1;
    *(uint2*)(s1 + (size_t)node * 16 + j0) = pk.u;
  }
}

union H8 { float4 f4; __half2 h2[4]; };

// accumulate one 16 B half-row (8 halfs) into 8 fp32 accumulators
__device__ __forceinline__ void acc8(const __half* __restrict__ tbl, int src, int h,
                                     float* __restrict__ a) {
  H8 w; w.f4 = *(const float4*)(tbl + ((size_t)src << 4) + (h << 3));
  float2 f0 = __half22float2(w.h2[0]); a[0] += f0.x; a[1] += f0.y;
  float2 f1 = __half22float2(w.h2[1]); a[2] += f1.x; a[3] += f1.y;
  float2 f2 = __half22float2(w.h2[2]); a[4] += f2.x; a[5] += f2.y;
  float2 f3 = __half22float2(w.h2[3]); a[6] += f3.x; a[7] += f3.y;
}

// wide gather, branchless main loop: 8 threads/node = 4 edge-lanes (el) x 2
// half-rows (h). pairs read as aligned int4; <=3-edge head/tail handled by
// predicated scalar reads on separate lanes (no exec-mask churn in the loop).
__device__ __forceinline__ void gather_w(const __half* __restrict__ tbl,
                                         const int* __restrict__ pairs,
                                         int s, int en, int el, int h,
                                         float* __restrict__ a) {
  int su = (s + 3) & ~3;            // first aligned int4 boundary >= s
  int ed = en & ~3;                 // last aligned boundary <= en
  int he = min(su, en);             // head edges [s, he)
  int ts = max(ed, he);             // tail edges [ts, en)
  if (s + el < he) acc8(tbl, pairs[s + el], h, a);
  if (ts + el < en) acc8(tbl, pairs[ts + el], h, a);
  for (int j = su + (el << 2); j < ed - 3; j += 16) {
    int4 p = *(const int4*)(pairs + j);
    acc8(tbl, p.x, h, a); acc8(tbl, p.y, h, a);
    acc8(tbl, p.z, h, a); acc8(tbl, p.w, h, a);
  }
  // merge the 4 edge-lanes (xor masks 2,4 stay inside the 8-lane node group)
  #pragma unroll
  for (int k = 0; k < 8; k++) {
    a[k] += __shfl_xor(a[k], 2);
    a[k] += __shfl_xor(a[k], 4);
  }
}

// layer-1: degree-ordered wide-gather aggregation + fused relu/bias -> fp16 s2
__global__ __launch_bounds__(256) void agg1_kernel(const int* __restrict__ pairs,
                                                   const int* __restrict__ node_start,
                                                   const int* __restrict__ perm,
                                                   const __half* __restrict__ s1,
                                                   const float* __restrict__ dinv,
                                                   const float* __restrict__ b1,
                                                   __half* __restrict__ s2, int n) {
  __shared__ float lb1[16];
  __shared__ int pm[AGG_NODES];
  __shared__ int ns0[AGG_NODES];
  __shared__ int ns1[AGG_NODES];
  int t = threadIdx.x;
  int bn = blockIdx.x * AGG_NODES;
  if (t < 16) lb1[t] = b1[t];
  if (t < AGG_NODES) {
    int p = (bn + t < n) ? perm[bn + t] : -1;
    pm[t] = p;
    if (p >= 0) { ns0[t] = node_start[p]; ns1[t] = node_start[p + 1]; }
  }
  __syncthreads();
  int node_l = t >> 3;
  int el = (t >> 1) & 3;
  int h = t & 1;
  int node = pm[node_l];
  if (node < 0) return;      // uniform per 8-lane group
  float a[8] = {0.f, 0.f, 0.f, 0.f, 0.f, 0.f, 0.f, 0.f};
  if (el == 0) acc8(s1, node, h, a);   // self loop counted once per h
  gather_w(s1, pairs, ns0[node_l], ns1[node_l], el, h, a);
  if (el == 0) {
    float d = dinv[node];
    int f = h * 8;
    H8 o;
    #pragma unroll
    for (int k = 0; k < 4; k++) {
      float v0 = fmaxf(fmaf(d, a[2 * k],     lb1[f + 2 * k]),     0.f) * d;
      float v1 = fmaxf(fmaf(d, a[2 * k + 1], lb1[f + 2 * k + 1]), 0.f) * d;
      o.h2[k] = __floats2half2_rn(v0, v1);
    }
    *(float4*)(s2 + ((size_t)node << 4) + (h << 3)) = o.f4;   // 16 B store
  }
}

// layer-2: degree-ordered wide-gather aggregation + fused 16->64 transform
__global__ __launch_bounds__(256) void agg2_kernel(const int* __restrict__ pairs,
                                                   const int* __restrict__ node_start,
                                                   const int* __restrict__ perm,
                                                   const __half* __restrict__ s2,
                                                   const float* __restrict__ dinv,
                                                   const float* __restrict__ W2,
                                                   const float* __restrict__ b2,
                                                   float* __restrict__ out, int n) {
  __shared__ float tile[AGG_NODES * 16];   // pre-activation (exact ownership)
  __shared__ float w2s[16 * 64];
  __shared__ float b2s[64];
  __shared__ int pm[AGG_NODES];
  __shared__ int ns0[AGG_NODES];
  __shared__ int ns1[AGG_NODES];
  int t = threadIdx.x;
  int bn = blockIdx.x * AGG_NODES;
  for (int i = t; i < 16 * 64; i += 256) w2s[i] = W2[i];
  if (t < 64) b2s[t] = b2[t];
  if (t < AGG_NODES) {
    int p = (bn + t < n) ? perm[bn + t] : -1;
    pm[t] = p;
    if (p >= 0) { ns0[t] = node_start[p]; ns1[t] = node_start[p + 1]; }
  }
  __syncthreads();
  int node_l = t >> 3;
  int el = (t >> 1) & 3;
  int h = t & 1;
  int node = pm[node_l];
  if (node >= 0) {
    float a[8] = {0.f, 0.f, 0.f, 0.f, 0.f, 0.f, 0.f, 0.f};
    if (el == 0) acc8(s2, node, h, a);   // self loop
    gather_w(s2, pairs, ns0[node_l], ns1[node_l], el, h, a);
    if (el == 0) {
      float d = dinv[node];
      float* tp = tile + node_l * 16 + h * 8;
      #pragma unroll
      for (int k = 0; k < 8; k++) tp[k] = a[k] * d;
    }
  }
  __syncthreads();
  for (int idx = t; idx < AGG_NODES * 64; idx += 256) {
    int r = idx >> 6, jj = idx & 63;
    int onode = pm[r];
    if (onode >= 0) {
      float o = b2s[jj];
      #pragma unroll
      for (int k = 0; k < 16; k++) o = fmaf(tile[r * 16 + k], w2s[k * 64 + jj], o);
      out[(size_t)onode * 64 + jj] = o;   // 256 B contiguous per node
    }
  }
}

extern "C" void kernel_launch(void* const* d_in, const int* in_sizes, int n_in,
                              void* d_out, int out_size, void* d_ws, size_t ws_size,
                              hipStream_t stream) {
  const float* x = (const float*)d_in[0];
  const int* ei = (const int*)d_in[1];   // int32 (JAX x64 disabled)
  const float* W1 = (const float*)d_in[2];
  const float* b1 = (const float*)d_in[3];
  const float* W2 = (const float*)d_in[4];
  const float* b2 = (const float*)d_in[5];
  float* out = (float*)d_out;

  int n = in_sizes[0] / 128;   // 100000
  int e = in_sizes[1] / 2;     // 3200000
  const int* row = ei;         // sources
  const int* col = ei + e;     // targets (aggregation index)
  int nsb = (n + SB_SIZE - 1) >> SB_SHIFT;           // 391 super-buckets
  int nchunks = (e + BIN_CHUNK - 1) / BIN_CHUNK;     // 391 chunks

  // workspace layout (ints; regions 16B-aligned). s1/s2 overlap dead pairsA.
  int* bcnt = (int*)d_ws;                     // 512
  int* sbstart = bcnt + 512;                  // 528
  int* bcur = sbstart + 528;                  // 512
  int* degcnt = bcur + 512;                   // 256
  int* degoff = degcnt + 256;                 // 256
  int* cntM = degoff + 256;                   // nchunks*MAXSB (<= 800*512 = 1.6 MB)
  int* pairsA = cntM + 800 * MAXSB;           // e  (12.8 MB; dead after sortB)
  int* pairs = pairsA + e;                    // e  (12.8 MB)
  int* node_start = pairs + e;                // 512*256+16
  float* dinv = (float*)(node_start + 512 * 256 + 16);  // 512*256
  int* perm = (int*)dinv + 512 * 256;         // n ids in degree order
  __half* s1 = (__half*)pairsA;               // 16n halfs = 3.2 MB (inside pairsA)
  __half* s2 = s1 + (size_t)n * 16;           // 16n halfs = 3.2 MB (inside pairsA)

  // ---- node-sorted edge build + degree-ordered schedule (once) ----
  zero_i_kernel<<<5, 512, 0, stream>>>(bcnt, 512 + 528 + 512 + 256 + 256);
  histA_kernel<<<nchunks, BIN_THREADS, 0, stream>>>(col, bcnt, cntM, e, nsb);
  scanA_kernel<<<1, 512, 0, stream>>>(bcnt, sbstart, bcur, nsb);
  binA_kernel<<<nchunks, BIN_THREADS, 0, stream>>>(row, col, cntM, bcur, pairsA, e);
  sortB_kernel<<<nsb, 512, 0, stream>>>(pairsA, sbstart, pairs, node_start, dinv, degcnt, n);
  degscan_kernel<<<1, DEGB, 0, stream>>>(degcnt, degoff);
  degscat_kernel<<<(n + 255) / 256, 256, 0, stream>>>(node_start, degoff, perm, n);

  // ---- layer 1: transform (128->16) -> fp16 table, wide-gather aggregate ----
  mm1_kernel<<<(n + NODES_PER_BLOCK - 1) / NODES_PER_BLOCK, 256, 0, stream>>>(x, W1, dinv, s1, n);
  agg1_kernel<<<(n + AGG_NODES - 1) / AGG_NODES, 256, 0, stream>>>(pairs, node_start, perm, s1, dinv, b1, s2, n);

  // ---- layer 2: wide-gather aggregate + fused 16->64 transform ----
  agg2_kernel<<<(n + AGG_NODES - 1) / AGG_NODES, 256, 0, stream>>>(pairs, node_start, perm, s2, dinv, W2, b2, out, n);
}

// Round 9
// 254.701 us; speedup vs baseline: 2.7282x; 2.7282x over previous
//
#include <hip/hip_runtime.h>
#include <hip/hip_fp16.h>

// ---- shape constants (N=100000 <= 131072 so src fits in 17 bits) ----
#define SB_SHIFT 8
#define SB_SIZE 256             // nodes per super-bucket (sortB parallelism: nsb=391)
#define MAXSB 512               // padded super-bucket array size
#define BIN_CHUNK 8192          // edges per chunk -> 391 blocks
#define BIN_THREADS 1024        // 16 waves/block -> ~12 waves/CU
#define SRC_BITS 17
#define SRC_MASK 0x1FFFF
#define NODES_PER_BLOCK 64      // mm1 tile
#define AGG_NODES 32            // nodes per agg block (256 threads, 8/node)
#define DEGB 256                // degree buckets for counting sort

__global__ void zero_i_kernel(int* __restrict__ p, int total) {
  int i = blockIdx.x * blockDim.x + threadIdx.x;
  if (i < total) p[i] = 0;
}

// per-chunk histogram of col>>8 -> cntM[chunk][*], plus global totals bcnt
__global__ __launch_bounds__(BIN_THREADS) void histA_kernel(const int* __restrict__ col,
                                                            int* __restrict__ bcnt,
                                                            int* __restrict__ cntM,
                                                            int e, int nsb) {
  __shared__ int lc[MAXSB];
  int t = threadIdx.x;
  int chunk = blockIdx.x;
  int i0 = chunk * BIN_CHUNK;
  int i1 = min(i0 + BIN_CHUNK, e);
  if (t < MAXSB) lc[t] = 0;
  __syncthreads();
  for (int i = i0 + t; i < i1; i += BIN_THREADS)
    atomicAdd(&lc[col[i] >> SB_SHIFT], 1);
  __syncthreads();
  int* cm = cntM + (size_t)chunk * MAXSB;
  if (t < MAXSB) {
    int v = lc[t];
    cm[t] = v;
    if (t < nsb && v) atomicAdd(&bcnt[t], v);
  }
}

// exclusive scan over nsb (<=512) counts -> sbstart[0..nsb], bcur copy
__global__ __launch_bounds__(512) void scanA_kernel(const int* __restrict__ bcnt,
                                                    int* __restrict__ sbstart,
                                                    int* __restrict__ bcur, int nsb) {
  __shared__ int lds[512];
  int t = threadIdx.x;
  int v = (t < nsb) ? bcnt[t] : 0;
  lds[t] = v;
  __syncthreads();
  for (int off = 1; off < 512; off <<= 1) {
    int u = (t >= off) ? lds[t - off] : 0;
    __syncthreads();
    lds[t] += u;
    __syncthreads();
  }
  int excl = lds[t] - v;
  if (t < nsb) { sbstart[t] = excl; bcur[t] = excl; }
  if (t == 511) sbstart[nsb] = lds[511];
}

// pass A: LDS-staged radix partition into super-bucket groups.
// Scatter goes to LDS (cheap); global write is a linear sweep -> wave-coalesced
// full-line writes, bounded amplification regardless of run length.
// pairsA = src | colLow8<<17
__global__ __launch_bounds__(BIN_THREADS) void binA_kernel(const int* __restrict__ row,
                                                           const int* __restrict__ col,
                                                           const int* __restrict__ cntM,
                                                           int* __restrict__ bcur,
                                                           int* __restrict__ pairsA, int e) {
  __shared__ int stage[BIN_CHUNK];   // 32 KB staging
  __shared__ int cm[MAXSB];
  __shared__ int gbase[MAXSB];
  __shared__ int lb[MAXSB];          // exclusive local base (after scan)
  __shared__ int lcur[MAXSB];
  int t = threadIdx.x;
  int chunk = blockIdx.x;
  int i0 = chunk * BIN_CHUNK;
  int i1 = min(i0 + BIN_CHUNK, e);
  int csize = i1 - i0;
  const int* cmg = cntM + (size_t)chunk * MAXSB;
  if (t < MAXSB) {
    int c = cmg[t];
    cm[t] = c;
    gbase[t] = c ? atomicAdd(&bcur[t], c) : 0;
    lb[t] = c;
  }
  __syncthreads();
  // Hillis-Steele inclusive scan on lb[0..511]
  for (int off = 1; off < MAXSB; off <<= 1) {
    int u = (t < MAXSB && t >= off) ? lb[t - off] : 0;
    __syncthreads();
    if (t < MAXSB) lb[t] += u;
    __syncthreads();
  }
  if (t < MAXSB) {
    int ex = lb[t] - cm[t];   // exclusive base
    lb[t] = ex;
    lcur[t] = ex;
  }
  __syncthreads();
  // scatter into LDS staging, grouped by bucket
  for (int i = i0 + t; i < i1; i += BIN_THREADS) {
    int c = col[i];
    int b = c >> SB_SHIFT;
    int p = atomicAdd(&lcur[b], 1);
    stage[p] = row[i] | ((c & (SB_SIZE - 1)) << SRC_BITS);
  }
  __syncthreads();
  // linear flush: consecutive p -> consecutive dest within each bucket run
  for (int p = t; p < csize; p += BIN_THREADS) {
    int b = 0;
    #pragma unroll
    for (int step = 256; step > 0; step >>= 1) {
      int nb = b + step;
      if (nb < MAXSB && lb[nb] <= p) b = nb;
    }
    pairsA[gbase[b] + (p - lb[b])] = stage[p];
  }
}

// pass B: per super-bucket counting sort by local col -> node-sorted src array.
// node_start[], dinv[] fall out of the count; degree histogram is LDS-aggregated
// per block then merged (NOT per-node global atomics -- r8 lesson: 100K atomics
// onto ~40 addresses fully serialize, 244us).
__global__ __launch_bounds__(512) void sortB_kernel(const int* __restrict__ pairsA,
                                                    const int* __restrict__ sbstart,
                                                    int* __restrict__ pairs,
                                                    int* __restrict__ node_start,
                                                    float* __restrict__ dinv,
                                                    int* __restrict__ degcnt, int n) {
  __shared__ int cnt[SB_SIZE];
  __shared__ int base[SB_SIZE];
  __shared__ int cur[SB_SIZE];
  __shared__ int dh[DEGB];
  int b = blockIdx.x, t = threadIdx.x;
  int e0 = sbstart[b], e1 = sbstart[b + 1];
  if (t < SB_SIZE) cnt[t] = 0;
  if (t >= SB_SIZE && t < SB_SIZE + DEGB) dh[t - SB_SIZE] = 0;
  __syncthreads();
  for (int i = e0 + t; i < e1; i += 512) atomicAdd(&cnt[pairsA[i] >> SRC_BITS], 1);
  __syncthreads();
  if (t < SB_SIZE) base[t] = cnt[t];
  __syncthreads();
  for (int off = 1; off < SB_SIZE; off <<= 1) {
    int u = (t < SB_SIZE && t >= off) ? base[t - off] : 0;
    __syncthreads();
    if (t < SB_SIZE) base[t] += u;
    __syncthreads();
  }
  if (t < SB_SIZE) {
    int excl = base[t] - cnt[t];
    cur[t] = excl;
    int node = (b << SB_SHIFT) + t;
    node_start[node] = e0 + excl;
    dinv[node] = rsqrtf((float)cnt[t] + 1.0f);
    if (node < n) atomicAdd(&dh[min(cnt[t], DEGB - 1)], 1);   // LDS histogram
  }
  __syncthreads();
  if (t < DEGB) {
    int v = dh[t];
    if (v) atomicAdd(&degcnt[t], v);   // ~40 spread global atomics per block
  }
  for (int i = e0 + t; i < e1; i += 512) {
    int v = pairsA[i];
    int pos = e0 + atomicAdd(&cur[v >> SRC_BITS], 1);
    pairs[pos] = v & SRC_MASK;
  }
}

// exclusive scan of degree-bucket counts (256, one block)
__global__ __launch_bounds__(DEGB) void degscan_kernel(const int* __restrict__ degcnt,
                                                       int* __restrict__ degoff) {
  __shared__ int lds[DEGB];
  int t = threadIdx.x;
  int v = degcnt[t];
  lds[t] = v;
  __syncthreads();
  for (int off = 1; off < DEGB; off <<= 1) {
    int u = (t >= off) ? lds[t - off] : 0;
    __syncthreads();
    lds[t] += u;
    __syncthreads();
  }
  degoff[t] = lds[t] - v;
}

// counting-sort scatter: perm = node ids in ascending-degree order.
// Two-level: LDS histogram -> one range-reservation atomic per (block,bucket)
// -> local-rank placement. Order within a bucket arbitrary (sums unaffected).
__global__ __launch_bounds__(256) void degscat_kernel(const int* __restrict__ node_start,
                                                      int* __restrict__ degoff,
                                                      int* __restrict__ perm, int n) {
  __shared__ int lh[DEGB];
  __shared__ int lbase[DEGB];
  int t = threadIdx.x;
  int i = blockIdx.x * 256 + t;
  lh[t] = 0;
  __syncthreads();
  int d = -1;
  if (i < n) {
    d = min(node_start[i + 1] - node_start[i], DEGB - 1);
    atomicAdd(&lh[d], 1);              // LDS atomic
  }
  __syncthreads();
  int c = lh[t];
  if (c) lbase[t] = atomicAdd(&degoff[t], c);   // reserve contiguous range
  __syncthreads();
  lh[t] = 0;                           // reuse as local cursor
  __syncthreads();
  if (i < n) {
    int r = atomicAdd(&lh[d], 1);      // local rank within (block,bucket)
    perm[lbase[d] + r] = i;
  }
}

// s1 = fp16( (x @ W1) * dinv ) ; 32 B/row -> L2-resident table
__global__ __launch_bounds__(256) void mm1_kernel(const float* __restrict__ x,
                                                  const float* __restrict__ W1,
                                                  const float* __restrict__ dinv,
                                                  __half* __restrict__ s1, int n) {
  __shared__ float xs[NODES_PER_BLOCK][129];
  __shared__ float ws[128 * 16];
  int t = threadIdx.x;
  for (int i = t; i < 128 * 16; i += 256) ws[i] = W1[i];
  int base = blockIdx.x * NODES_PER_BLOCK;
  for (int i = t * 4; i < NODES_PER_BLOCK * 128; i += 256 * 4) {
    int nn = i >> 7, k = i & 127;
    if (base + nn < n) {
      float4 v = *(const float4*)(x + (size_t)(base + nn) * 128 + k);
      xs[nn][k] = v.x; xs[nn][k + 1] = v.y; xs[nn][k + 2] = v.z; xs[nn][k + 3] = v.w;
    }
  }
  __syncthreads();
  int nn = t >> 2;
  int j0 = (t & 3) * 4;
  float a0 = 0, a1 = 0, a2 = 0, a3 = 0;
  #pragma unroll 8
  for (int k = 0; k < 128; k++) {
    float xv = xs[nn][k];
    const float* wr = ws + k * 16 + j0;
    a0 += xv * wr[0]; a1 += xv * wr[1]; a2 += xv * wr[2]; a3 += xv * wr[3];
  }
  int node = base + nn;
  if (node < n) {
    float d = dinv[node];
    __half2 p0 = __floats2half2_rn(a0 * d, a1 * d);
    __half2 p1 = __floats2half2_rn(a2 * d, a3 * d);
    union { struct { __half2 a, b; } h; uint2 u; } pk;
    pk.h.a = p0; pk.h.b = p1;
    *(uint2*)(s1 + (size_t)node * 16 + j0) = pk.u;
  }
}

union H8 { float4 f4; __half2 h2[4]; };

// accumulate one 16 B half-row (8 halfs) into 8 fp32 accumulators
__device__ __forceinline__ void acc8(const __half* __restrict__ tbl, int src, int h,
                                     float* __restrict__ a) {
  H8 w; w.f4 = *(const float4*)(tbl + ((size_t)src << 4) + (h << 3));
  float2 f0 = __half22float2(w.h2[0]); a[0] += f0.x; a[1] += f0.y;
  float2 f1 = __half22float2(w.h2[1]); a[2] += f1.x; a[3] += f1.y;
  float2 f2 = __half22float2(w.h2[2]); a[4] += f2.x; a[5] += f2.y;
  float2 f3 = __half22float2(w.h2[3]); a[6] += f3.x; a[7] += f3.y;
}

// wide gather, branchless main loop: 8 threads/node = 4 edge-lanes (el) x 2
// half-rows (h). pairs read as aligned int4; <=3-edge head/tail handled by
// predicated scalar reads on separate lanes (no exec-mask churn in the loop).
__device__ __forceinline__ void gather_w(const __half* __restrict__ tbl,
                                         const int* __restrict__ pairs,
                                         int s, int en, int el, int h,
                                         float* __restrict__ a) {
  int su = (s + 3) & ~3;            // first aligned int4 boundary >= s
  int ed = en & ~3;                 // last aligned boundary <= en
  int he = min(su, en);             // head edges [s, he)
  int ts = max(ed, he);             // tail edges [ts, en)
  if (s + el < he) acc8(tbl, pairs[s + el], h, a);
  if (ts + el < en) acc8(tbl, pairs[ts + el], h, a);
  for (int j = su + (el << 2); j < ed - 3; j += 16) {
    int4 p = *(const int4*)(pairs + j);
    acc8(tbl, p.x, h, a); acc8(tbl, p.y, h, a);
    acc8(tbl, p.z, h, a); acc8(tbl, p.w, h, a);
  }
  // merge the 4 edge-lanes (xor masks 2,4 stay inside the 8-lane node group)
  #pragma unroll
  for (int k = 0; k < 8; k++) {
    a[k] += __shfl_xor(a[k], 2);
    a[k] += __shfl_xor(a[k], 4);
  }
}

// layer-1: degree-ordered wide-gather aggregation + fused relu/bias -> fp16 s2
__global__ __launch_bounds__(256) void agg1_kernel(const int* __restrict__ pairs,
                                                   const int* __restrict__ node_start,
                                                   const int* __restrict__ perm,
                                                   const __half* __restrict__ s1,
                                                   const float* __restrict__ dinv,
                                                   const float* __restrict__ b1,
                                                   __half* __restrict__ s2, int n) {
  __shared__ float lb1[16];
  __shared__ int pm[AGG_NODES];
  __shared__ int ns0[AGG_NODES];
  __shared__ int ns1[AGG_NODES];
  int t = threadIdx.x;
  int bn = blockIdx.x * AGG_NODES;
  if (t < 16) lb1[t] = b1[t];
  if (t < AGG_NODES) {
    int p = (bn + t < n) ? perm[bn + t] : -1;
    pm[t] = p;
    if (p >= 0) { ns0[t] = node_start[p]; ns1[t] = node_start[p + 1]; }
  }
  __syncthreads();
  int node_l = t >> 3;
  int el = (t >> 1) & 3;
  int h = t & 1;
  int node = pm[node_l];
  if (node < 0) return;      // uniform per 8-lane group
  float a[8] = {0.f, 0.f, 0.f, 0.f, 0.f, 0.f, 0.f, 0.f};
  if (el == 0) acc8(s1, node, h, a);   // self loop counted once per h
  gather_w(s1, pairs, ns0[node_l], ns1[node_l], el, h, a);
  if (el == 0) {
    float d = dinv[node];
    int f = h * 8;
    H8 o;
    #pragma unroll
    for (int k = 0; k < 4; k++) {
      float v0 = fmaxf(fmaf(d, a[2 * k],     lb1[f + 2 * k]),     0.f) * d;
      float v1 = fmaxf(fmaf(d, a[2 * k + 1], lb1[f + 2 * k + 1]), 0.f) * d;
      o.h2[k] = __floats2half2_rn(v0, v1);
    }
    *(float4*)(s2 + ((size_t)node << 4) + (h << 3)) = o.f4;   // 16 B store
  }
}

// layer-2: degree-ordered wide-gather aggregation + fused 16->64 transform
__global__ __launch_bounds__(256) void agg2_kernel(const int* __restrict__ pairs,
                                                   const int* __restrict__ node_start,
                                                   const int* __restrict__ perm,
                                                   const __half* __restrict__ s2,
                                                   const float* __restrict__ dinv,
                                                   const float* __restrict__ W2,
                                                   const float* __restrict__ b2,
                                                   float* __restrict__ out, int n) {
  __shared__ float tile[AGG_NODES * 16];   // pre-activation (exact ownership)
  __shared__ float w2s[16 * 64];
  __shared__ float b2s[64];
  __shared__ int pm[AGG_NODES];
  __shared__ int ns0[AGG_NODES];
  __shared__ int ns1[AGG_NODES];
  int t = threadIdx.x;
  int bn = blockIdx.x * AGG_NODES;
  for (int i = t; i < 16 * 64; i += 256) w2s[i] = W2[i];
  if (t < 64) b2s[t] = b2[t];
  if (t < AGG_NODES) {
    int p = (bn + t < n) ? perm[bn + t] : -1;
    pm[t] = p;
    if (p >= 0) { ns0[t] = node_start[p]; ns1[t] = node_start[p + 1]; }
  }
  __syncthreads();
  int node_l = t >> 3;
  int el = (t >> 1) & 3;
  int h = t & 1;
  int node = pm[node_l];
  if (node >= 0) {
    float a[8] = {0.f, 0.f, 0.f, 0.f, 0.f, 0.f, 0.f, 0.f};
    if (el == 0) acc8(s2, node, h, a);   // self loop
    gather_w(s2, pairs, ns0[node_l], ns1[node_l], el, h, a);
    if (el == 0) {
      float d = dinv[node];
      float* tp = tile + node_l * 16 + h * 8;
      #pragma unroll
      for (int k = 0; k < 8; k++) tp[k] = a[k] * d;
    }
  }
  __syncthreads();
  for (int idx = t; idx < AGG_NODES * 64; idx += 256) {
    int r = idx >> 6, jj = idx & 63;
    int onode = pm[r];
    if (onode >= 0) {
      float o = b2s[jj];
      #pragma unroll
      for (int k = 0; k < 16; k++) o = fmaf(tile[r * 16 + k], w2s[k * 64 + jj], o);
      out[(size_t)onode * 64 + jj] = o;   // 256 B contiguous per node
    }
  }
}

extern "C" void kernel_launch(void* const* d_in, const int* in_sizes, int n_in,
                              void* d_out, int out_size, void* d_ws, size_t ws_size,
                              hipStream_t stream) {
  const float* x = (const float*)d_in[0];
  const int* ei = (const int*)d_in[1];   // int32 (JAX x64 disabled)
  const float* W1 = (const float*)d_in[2];
  const float* b1 = (const float*)d_in[3];
  const float* W2 = (const float*)d_in[4];
  const float* b2 = (const float*)d_in[5];
  float* out = (float*)d_out;

  int n = in_sizes[0] / 128;   // 100000
  int e = in_sizes[1] / 2;     // 3200000
  const int* row = ei;         // sources
  const int* col = ei + e;     // targets (aggregation index)
  int nsb = (n + SB_SIZE - 1) >> SB_SHIFT;           // 391 super-buckets
  int nchunks = (e + BIN_CHUNK - 1) / BIN_CHUNK;     // 391 chunks

  // workspace layout (ints; regions 16B-aligned). s1/s2 overlap dead pairsA.
  int* bcnt = (int*)d_ws;                     // 512
  int* sbstart = bcnt + 512;                  // 528
  int* bcur = sbstart + 528;                  // 512
  int* degcnt = bcur + 512;                   // 256
  int* degoff = degcnt + 256;                 // 256
  int* cntM = degoff + 256;                   // nchunks*MAXSB (<= 800*512 = 1.6 MB)
  int* pairsA = cntM + 800 * MAXSB;           // e  (12.8 MB; dead after sortB)
  int* pairs = pairsA + e;                    // e  (12.8 MB)
  int* node_start = pairs + e;                // 512*256+16
  float* dinv = (float*)(node_start + 512 * 256 + 16);  // 512*256
  int* perm = (int*)dinv + 512 * 256;         // n ids in degree order
  __half* s1 = (__half*)pairsA;               // 16n halfs = 3.2 MB (inside pairsA)
  __half* s2 = s1 + (size_t)n * 16;           // 16n halfs = 3.2 MB (inside pairsA)

  // ---- node-sorted edge build + degree-ordered schedule (once) ----
  zero_i_kernel<<<5, 512, 0, stream>>>(bcnt, 512 + 528 + 512 + 256 + 256);
  histA_kernel<<<nchunks, BIN_THREADS, 0, stream>>>(col, bcnt, cntM, e, nsb);
  scanA_kernel<<<1, 512, 0, stream>>>(bcnt, sbstart, bcur, nsb);
  binA_kernel<<<nchunks, BIN_THREADS, 0, stream>>>(row, col, cntM, bcur, pairsA, e);
  sortB_kernel<<<nsb, 512, 0, stream>>>(pairsA, sbstart, pairs, node_start, dinv, degcnt, n);
  degscan_kernel<<<1, DEGB, 0, stream>>>(degcnt, degoff);
  degscat_kernel<<<(n + 255) / 256, 256, 0, stream>>>(node_start, degoff, perm, n);

  // ---- layer 1: transform (128->16) -> fp16 table, wide-gather aggregate ----
  mm1_kernel<<<(n + NODES_PER_BLOCK - 1) / NODES_PER_BLOCK, 256, 0, stream>>>(x, W1, dinv, s1, n);
  agg1_kernel<<<(n + AGG_NODES - 1) / AGG_NODES, 256, 0, stream>>>(pairs, node_start, perm, s1, dinv, b1, s2, n);

  // ---- layer 2: wide-gather aggregate + fused 16->64 transform ----
  agg2_kernel<<<(n + AGG_NODES - 1) / AGG_NODES, 256, 0, stream>>>(pairs, node_start, perm, s2, dinv, W2, b2, out, n);
}

// Round 10
// 224.930 us; speedup vs baseline: 3.0893x; 1.1324x over previous
//
#include <hip/hip_runtime.h>
#include <hip/hip_fp16.h>

// ---- shape constants (N=100000 <= 131072 so src fits in 17 bits) ----
#define SB_SHIFT 8
#define SB_SIZE 256             // nodes per super-bucket (nsb=391)
#define MAXSB 512               // padded super-bucket array size
#define BIN_CHUNK 8192          // edges per chunk -> 391 blocks
#define BIN_THREADS 1024        // 16 waves/block
#define BCAP 10240              // per-bucket capacity (E[fill]=8192, +22 sigma)
#define SRC_BITS 17
#define SRC_MASK 0x1FFFF
#define NODES_PER_BLOCK 64      // mm1 tile
#define AGG_NODES 32            // nodes per agg block (256 threads, 8/node)

// bcur[b] = b*BCAP (start of bucket b's capacity region)
__global__ __launch_bounds__(512) void initb_kernel(int* __restrict__ bcur) {
  int i = threadIdx.x;
  bcur[i] = i * BCAP;
}

// fused hist + LDS-staged radix partition into capacity-padded bucket regions.
// Self-counts its chunk (no separate histA/scanA pass -- bucket bases come from
// one atomicAdd per (chunk,bucket) on the capacity cursors). Scatter goes to
// LDS; global write is a linear sweep -> wave-coalesced full-line writes.
// pairsA = src | colLow8<<17
__global__ __launch_bounds__(BIN_THREADS) void binA_kernel(const int* __restrict__ row,
                                                           const int* __restrict__ col,
                                                           int* __restrict__ bcur,
                                                           int* __restrict__ pairsA, int e) {
  __shared__ int stage[BIN_CHUNK];   // 32 KB staging
  __shared__ int lc[MAXSB];          // local counts (kept through scan)
  __shared__ int gbase[MAXSB];
  __shared__ int lb[MAXSB];          // exclusive local base (after scan)
  __shared__ int lcur[MAXSB];
  int t = threadIdx.x;
  int chunk = blockIdx.x;
  int i0 = chunk * BIN_CHUNK;
  int i1 = min(i0 + BIN_CHUNK, e);
  int csize = i1 - i0;
  if (t < MAXSB) lc[t] = 0;
  __syncthreads();
  for (int i = i0 + t; i < i1; i += BIN_THREADS)
    atomicAdd(&lc[col[i] >> SB_SHIFT], 1);
  __syncthreads();
  if (t < MAXSB) {
    int c = lc[t];
    lb[t] = c;
    gbase[t] = c ? atomicAdd(&bcur[t], c) : 0;  // reserve run in bucket region
  }
  __syncthreads();
  // Hillis-Steele inclusive scan on lb[0..511]
  for (int off = 1; off < MAXSB; off <<= 1) {
    int u = (t < MAXSB && t >= off) ? lb[t - off] : 0;
    __syncthreads();
    if (t < MAXSB) lb[t] += u;
    __syncthreads();
  }
  if (t < MAXSB) {
    int ex = lb[t] - lc[t];   // exclusive base
    lb[t] = ex;
    lcur[t] = ex;
  }
  __syncthreads();
  // scatter into LDS staging, grouped by bucket (col is L2-hot from hist pass)
  for (int i = i0 + t; i < i1; i += BIN_THREADS) {
    int c = col[i];
    int b = c >> SB_SHIFT;
    int p = atomicAdd(&lcur[b], 1);
    stage[p] = row[i] | ((c & (SB_SIZE - 1)) << SRC_BITS);
  }
  __syncthreads();
  // linear flush: consecutive p -> consecutive dest within each bucket run
  for (int p = t; p < csize; p += BIN_THREADS) {
    int b = 0;
    #pragma unroll
    for (int step = 256; step > 0; step >>= 1) {
      int nb = b + step;
      if (nb < MAXSB && lb[nb] <= p) b = nb;
    }
    pairsA[gbase[b] + (p - lb[b])] = stage[p];
  }
}

// per super-bucket counting sort by local col -> node-grouped src array.
// Bucket range = [b*BCAP, bcur[b]). node_start/node_end/dinv fall out of the
// count for free. Output pairs is capacity-padded too (gaps between buckets),
// hence the explicit node_end array.
__global__ __launch_bounds__(512) void sortB_kernel(const int* __restrict__ pairsA,
                                                    const int* __restrict__ bcur,
                                                    int* __restrict__ pairs,
                                                    int* __restrict__ node_start,
                                                    int* __restrict__ node_end,
                                                    float* __restrict__ dinv, int n) {
  __shared__ int cnt[SB_SIZE];
  __shared__ int base[SB_SIZE];
  __shared__ int cur[SB_SIZE];
  int b = blockIdx.x, t = threadIdx.x;
  int e0 = b * BCAP, e1 = bcur[b];
  if (t < SB_SIZE) cnt[t] = 0;
  __syncthreads();
  for (int i = e0 + t; i < e1; i += 512) atomicAdd(&cnt[pairsA[i] >> SRC_BITS], 1);
  __syncthreads();
  if (t < SB_SIZE) base[t] = cnt[t];
  __syncthreads();
  for (int off = 1; off < SB_SIZE; off <<= 1) {
    int u = (t < SB_SIZE && t >= off) ? base[t - off] : 0;
    __syncthreads();
    if (t < SB_SIZE) base[t] += u;
    __syncthreads();
  }
  if (t < SB_SIZE) {
    int excl = base[t] - cnt[t];
    cur[t] = excl;
    int node = (b << SB_SHIFT) + t;
    node_start[node] = e0 + excl;
    node_end[node] = e0 + excl + cnt[t];
    dinv[node] = rsqrtf((float)cnt[t] + 1.0f);
  }
  __syncthreads();
  for (int i = e0 + t; i < e1; i += 512) {
    int v = pairsA[i];
    int pos = e0 + atomicAdd(&cur[v >> SRC_BITS], 1);
    pairs[pos] = v & SRC_MASK;
  }
}

// s1 = fp16( (x @ W1) * dinv ) ; 32 B/row -> L2-resident table
__global__ __launch_bounds__(256) void mm1_kernel(const float* __restrict__ x,
                                                  const float* __restrict__ W1,
                                                  const float* __restrict__ dinv,
                                                  __half* __restrict__ s1, int n) {
  __shared__ float xs[NODES_PER_BLOCK][129];
  __shared__ float ws[128 * 16];
  int t = threadIdx.x;
  for (int i = t; i < 128 * 16; i += 256) ws[i] = W1[i];
  int base = blockIdx.x * NODES_PER_BLOCK;
  for (int i = t * 4; i < NODES_PER_BLOCK * 128; i += 256 * 4) {
    int nn = i >> 7, k = i & 127;
    if (base + nn < n) {
      float4 v = *(const float4*)(x + (size_t)(base + nn) * 128 + k);
      xs[nn][k] = v.x; xs[nn][k + 1] = v.y; xs[nn][k + 2] = v.z; xs[nn][k + 3] = v.w;
    }
  }
  __syncthreads();
  int nn = t >> 2;
  int j0 = (t & 3) * 4;
  float a0 = 0, a1 = 0, a2 = 0, a3 = 0;
  #pragma unroll 8
  for (int k = 0; k < 128; k++) {
    float xv = xs[nn][k];
    const float* wr = ws + k * 16 + j0;
    a0 += xv * wr[0]; a1 += xv * wr[1]; a2 += xv * wr[2]; a3 += xv * wr[3];
  }
  int node = base + nn;
  if (node < n) {
    float d = dinv[node];
    __half2 p0 = __floats2half2_rn(a0 * d, a1 * d);
    __half2 p1 = __floats2half2_rn(a2 * d, a3 * d);
    union { struct { __half2 a, b; } h; uint2 u; } pk;
    pk.h.a = p0; pk.h.b = p1;
    *(uint2*)(s1 + (size_t)node * 16 + j0) = pk.u;
  }
}

union H8 { float4 f4; __half2 h2[4]; };

// accumulate one 16 B half-row (8 halfs) into 8 fp32 accumulators
__device__ __forceinline__ void acc8(const __half* __restrict__ tbl, int src, int h,
                                     float* __restrict__ a) {
  H8 w; w.f4 = *(const float4*)(tbl + ((size_t)src << 4) + (h << 3));
  float2 f0 = __half22float2(w.h2[0]); a[0] += f0.x; a[1] += f0.y;
  float2 f1 = __half22float2(w.h2[1]); a[2] += f1.x; a[3] += f1.y;
  float2 f2 = __half22float2(w.h2[2]); a[4] += f2.x; a[5] += f2.y;
  float2 f3 = __half22float2(w.h2[3]); a[6] += f3.x; a[7] += f3.y;
}

// wide gather, branchless main loop: 8 threads/node = 4 edge-lanes (el) x 2
// half-rows (h). pairs read as aligned int4; <=3-edge head/tail handled by
// predicated scalar reads on separate lanes (no exec-mask churn in the loop).
__device__ __forceinline__ void gather_w(const __half* __restrict__ tbl,
                                         const int* __restrict__ pairs,
                                         int s, int en, int el, int h,
                                         float* __restrict__ a) {
  int su = (s + 3) & ~3;            // first aligned int4 boundary >= s
  int ed = en & ~3;                 // last aligned boundary <= en
  int he = min(su, en);             // head edges [s, he)
  int ts = max(ed, he);             // tail edges [ts, en)
  if (s + el < he) acc8(tbl, pairs[s + el], h, a);
  if (ts + el < en) acc8(tbl, pairs[ts + el], h, a);
  for (int j = su + (el << 2); j < ed - 3; j += 16) {
    int4 p = *(const int4*)(pairs + j);
    acc8(tbl, p.x, h, a); acc8(tbl, p.y, h, a);
    acc8(tbl, p.z, h, a); acc8(tbl, p.w, h, a);
  }
  // merge the 4 edge-lanes (xor masks 2,4 stay inside the 8-lane node group)
  #pragma unroll
  for (int k = 0; k < 8; k++) {
    a[k] += __shfl_xor(a[k], 2);
    a[k] += __shfl_xor(a[k], 4);
  }
}

// layer-1: wide-gather aggregation + fused relu/bias/rescale -> fp16 s2
__global__ __launch_bounds__(256) void agg1_kernel(const int* __restrict__ pairs,
                                                   const int* __restrict__ node_start,
                                                   const int* __restrict__ node_end,
                                                   const __half* __restrict__ s1,
                                                   const float* __restrict__ dinv,
                                                   const float* __restrict__ b1,
                                                   __half* __restrict__ s2, int n) {
  __shared__ float lb1[16];
  __shared__ int ns0[AGG_NODES];
  __shared__ int ns1[AGG_NODES];
  int t = threadIdx.x;
  int bn = blockIdx.x * AGG_NODES;
  if (t < 16) lb1[t] = b1[t];
  if (t < AGG_NODES && bn + t < n) {
    ns0[t] = node_start[bn + t];
    ns1[t] = node_end[bn + t];
  }
  __syncthreads();
  int node_l = t >> 3;
  int el = (t >> 1) & 3;
  int h = t & 1;
  int node = bn + node_l;
  if (node >= n) return;     // uniform per 8-lane group
  float a[8] = {0.f, 0.f, 0.f, 0.f, 0.f, 0.f, 0.f, 0.f};
  if (el == 0) acc8(s1, node, h, a);   // self loop counted once per h
  gather_w(s1, pairs, ns0[node_l], ns1[node_l], el, h, a);
  if (el == 0) {
    float d = dinv[node];
    int f = h * 8;
    H8 o;
    #pragma unroll
    for (int k = 0; k < 4; k++) {
      float v0 = fmaxf(fmaf(d, a[2 * k],     lb1[f + 2 * k]),     0.f) * d;
      float v1 = fmaxf(fmaf(d, a[2 * k + 1], lb1[f + 2 * k + 1]), 0.f) * d;
      o.h2[k] = __floats2half2_rn(v0, v1);
    }
    *(float4*)(s2 + ((size_t)node << 4) + (h << 3)) = o.f4;   // 16 B store
  }
}

// layer-2: wide-gather aggregation + fused 16->64 transform -> out (fp32)
__global__ __launch_bounds__(256) void agg2_kernel(const int* __restrict__ pairs,
                                                   const int* __restrict__ node_start,
                                                   const int* __restrict__ node_end,
                                                   const __half* __restrict__ s2,
                                                   const float* __restrict__ dinv,
                                                   const float* __restrict__ W2,
                                                   const float* __restrict__ b2,
                                                   float* __restrict__ out, int n) {
  __shared__ float tile[AGG_NODES * 16];   // pre-activation (exact ownership)
  __shared__ float w2s[16 * 64];
  __shared__ float b2s[64];
  __shared__ int ns0[AGG_NODES];
  __shared__ int ns1[AGG_NODES];
  int t = threadIdx.x;
  int bn = blockIdx.x * AGG_NODES;
  for (int i = t; i < 16 * 64; i += 256) w2s[i] = W2[i];
  if (t < 64) b2s[t] = b2[t];
  if (t < AGG_NODES && bn + t < n) {
    ns0[t] = node_start[bn + t];
    ns1[t] = node_end[bn + t];
  }
  __syncthreads();
  int node_l = t >> 3;
  int el = (t >> 1) & 3;
  int h = t & 1;
  int node = bn + node_l;
  if (node < n) {
    float a[8] = {0.f, 0.f, 0.f, 0.f, 0.f, 0.f, 0.f, 0.f};
    if (el == 0) acc8(s2, node, h, a);   // self loop
    gather_w(s2, pairs, ns0[node_l], ns1[node_l], el, h, a);
    if (el == 0) {
      float d = dinv[node];
      float* tp = tile + node_l * 16 + h * 8;
      #pragma unroll
      for (int k = 0; k < 8; k++) tp[k] = a[k] * d;
    }
  }
  __syncthreads();
  for (int idx = t; idx < AGG_NODES * 64; idx += 256) {
    int r = idx >> 6, jj = idx & 63;
    int onode = bn + r;
    if (onode < n) {
      float o = b2s[jj];
      #pragma unroll
      for (int k = 0; k < 16; k++) o = fmaf(tile[r * 16 + k], w2s[k * 64 + jj], o);
      out[(size_t)onode * 64 + jj] = o;   // 256 B contiguous per node
    }
  }
}

extern "C" void kernel_launch(void* const* d_in, const int* in_sizes, int n_in,
                              void* d_out, int out_size, void* d_ws, size_t ws_size,
                              hipStream_t stream) {
  const float* x = (const float*)d_in[0];
  const int* ei = (const int*)d_in[1];   // int32 (JAX x64 disabled)
  const float* W1 = (const float*)d_in[2];
  const float* b1 = (const float*)d_in[3];
  const float* W2 = (const float*)d_in[4];
  const float* b2 = (const float*)d_in[5];
  float* out = (float*)d_out;

  int n = in_sizes[0] / 128;   // 100000
  int e = in_sizes[1] / 2;     // 3200000
  const int* row = ei;         // sources
  const int* col = ei + e;     // targets (aggregation index)
  int nsb = (n + SB_SIZE - 1) >> SB_SHIFT;           // 391 super-buckets
  int nchunks = (e + BIN_CHUNK - 1) / BIN_CHUNK;     // 391 chunks

  // workspace layout (ints; regions 16B-aligned). s1/s2 overlap dead pairsA.
  int* bcur = (int*)d_ws;                       // 512
  int* node_start = bcur + 512;                 // 512*256
  int* node_end = node_start + 512 * 256;       // 512*256
  float* dinv = (float*)(node_end + 512 * 256); // 512*256
  int* pairsA = (int*)dinv + 512 * 256;         // MAXSB*BCAP = 21 MB (dead after sortB)
  int* pairs = pairsA + (size_t)MAXSB * BCAP;   // MAXSB*BCAP = 21 MB
  __half* s1 = (__half*)pairsA;                 // 16n halfs = 3.2 MB (inside pairsA)
  __half* s2 = s1 + (size_t)n * 16;             // 16n halfs = 3.2 MB (inside pairsA)

  // ---- node-grouped edge build: fused-hist partition + bucket sort ----
  initb_kernel<<<1, 512, 0, stream>>>(bcur);
  binA_kernel<<<nchunks, BIN_THREADS, 0, stream>>>(row, col, bcur, pairsA, e);
  sortB_kernel<<<nsb, 512, 0, stream>>>(pairsA, bcur, pairs, node_start, node_end, dinv, n);

  // ---- layer 1: transform (128->16) -> fp16 table, wide-gather aggregate ----
  mm1_kernel<<<(n + NODES_PER_BLOCK - 1) / NODES_PER_BLOCK, 256, 0, stream>>>(x, W1, dinv, s1, n);
  agg1_kernel<<<(n + AGG_NODES - 1) / AGG_NODES, 256, 0, stream>>>(pairs, node_start, node_end, s1, dinv, b1, s2, n);

  // ---- layer 2: wide-gather aggregate + fused 16->64 transform ----
  agg2_kernel<<<(n + AGG_NODES - 1) / AGG_NODES, 256, 0, stream>>>(pairs, node_start, node_end, s2, dinv, W2, b2, out, n);
}